// Round 1
// baseline (23.232 us; speedup 1.0000x reference)
//
#include <hip/hip_runtime.h>

#define NN   50000
#define NE   800000
#define CH   64
#define NREL 8

// Kernel A: for every node, either splice the history row (the ~99.995% case)
// or initialize out = x @ loop_w + bias (self-loop) for uncached nodes.
// 16 threads per node, each handling a float4 (4 channels).
__global__ void splice_selfloop(const float* __restrict__ x,
                                const float* __restrict__ loop_w,
                                const float* __restrict__ bias,
                                const float* __restrict__ hist,
                                const int* __restrict__ hmap,
                                float* __restrict__ out) {
    int gid = blockIdx.x * blockDim.x + threadIdx.x;
    int n = gid >> 4;
    int q = gid & 15;
    if (n >= NN) return;
    int hm = hmap[n];
    float4* out4 = (float4*)out;
    if (hm >= 0) {
        const float4* h4 = (const float4*)hist;
        out4[n * 16 + q] = h4[hm * 16 + q];
    } else {
        int c0 = q * 4;
        float4 acc = ((const float4*)bias)[q];
        const float* xr = x + n * CH;
#pragma unroll 8
        for (int i = 0; i < CH; ++i) {
            float xv = xr[i];
            float4 w = *(const float4*)(loop_w + i * CH + c0);
            acc.x += xv * w.x;
            acc.y += xv * w.y;
            acc.z += xv * w.z;
            acc.w += xv * w.w;
        }
        out4[n * 16 + q] = acc;
    }
}

// Kernel B: compact the (rare) edges whose destination needs real compute.
__global__ void scan_edges(const int* __restrict__ dst,
                           const int* __restrict__ hmap,
                           int* __restrict__ count,
                           int* __restrict__ elist,
                           int cap) {
    int e = blockIdx.x * blockDim.x + threadIdx.x;
    if (e >= NE) return;
    int d = dst[e];
    if (hmap[d] < 0) {
        int pos = atomicAdd(count, 1);
        if (pos < cap) elist[pos] = e;
    }
}

// Kernel C: one wave per compacted edge; thread c computes
// msg[c] = sum_i x[src][i] * W[etype][i][c], atomically added into out[dst].
__global__ void edge_msgs(const float* __restrict__ x,
                          const float* __restrict__ W,
                          const int* __restrict__ src,
                          const int* __restrict__ dst,
                          const int* __restrict__ et,
                          const int* __restrict__ count,
                          const int* __restrict__ elist,
                          int cap,
                          float* __restrict__ out) {
    int cnt = *count;
    if (cnt > cap) cnt = cap;
    int c = threadIdx.x;
    for (int idx = blockIdx.x; idx < cnt; idx += gridDim.x) {
        int e = elist[idx];
        int s = src[e];
        int r = et[e];
        int d = dst[e];
        const float* xr = x + s * CH;
        const float* wr = W + r * CH * CH + c;
        float acc = 0.0f;
#pragma unroll 8
        for (int i = 0; i < CH; ++i)
            acc += xr[i] * wr[i * CH];
        atomicAdd(out + d * CH + c, acc);
    }
}

extern "C" void kernel_launch(void* const* d_in, const int* in_sizes, int n_in,
                              void* d_out, int out_size, void* d_ws, size_t ws_size,
                              hipStream_t stream) {
    const float* x      = (const float*)d_in[0];
    const float* W      = (const float*)d_in[1];
    const float* loop_w = (const float*)d_in[2];
    const float* bias   = (const float*)d_in[3];
    const float* hist   = (const float*)d_in[4];
    const int*   src    = (const int*)d_in[5];
    const int*   dst    = (const int*)d_in[6];
    const int*   et     = (const int*)d_in[7];
    const int*   hmap   = (const int*)d_in[8];
    float* out = (float*)d_out;

    int* count = (int*)d_ws;
    int* elist = (int*)((char*)d_ws + 256);
    long cap_l = ((long)ws_size - 256) / 4;
    int cap = cap_l < 0 ? 0 : (cap_l > NE ? NE : (int)cap_l);

    hipMemsetAsync(count, 0, sizeof(int), stream);

    splice_selfloop<<<(NN * 16 + 255) / 256, 256, 0, stream>>>(
        x, loop_w, bias, hist, hmap, out);

    scan_edges<<<(NE + 255) / 256, 256, 0, stream>>>(
        dst, hmap, count, elist, cap);

    edge_msgs<<<256, 64, 0, stream>>>(
        x, W, src, dst, et, count, elist, cap, out);
}

// Round 2
// 16.519 us; speedup vs baseline: 1.4064x; 1.4064x over previous
//
#include <hip/hip_runtime.h>

#define NN   50000
#define NE   800000
#define CH   64
#define NREL 8

// Kernel A: for every node, either splice the history row (the ~99.995% case)
// or initialize out = x @ loop_w + bias (self-loop) for uncached nodes.
// 16 threads per node, each handling a float4 (4 channels).
__global__ void splice_selfloop(const float* __restrict__ x,
                                const float* __restrict__ loop_w,
                                const float* __restrict__ bias,
                                const float* __restrict__ hist,
                                const int* __restrict__ hmap,
                                float* __restrict__ out) {
    int gid = blockIdx.x * blockDim.x + threadIdx.x;
    int n = gid >> 4;
    int q = gid & 15;
    if (n >= NN) return;
    int hm = hmap[n];
    float4* out4 = (float4*)out;
    if (hm >= 0) {
        const float4* h4 = (const float4*)hist;
        out4[n * 16 + q] = h4[hm * 16 + q];
    } else {
        int c0 = q * 4;
        float4 acc = ((const float4*)bias)[q];
        const float* xr = x + n * CH;
#pragma unroll 8
        for (int i = 0; i < CH; ++i) {
            float xv = xr[i];
            float4 w = *(const float4*)(loop_w + i * CH + c0);
            acc.x += xv * w.x;
            acc.y += xv * w.y;
            acc.z += xv * w.z;
            acc.w += xv * w.w;
        }
        out4[n * 16 + q] = acc;
    }
}

// Kernel B+C fused: each wave scans 64 edges (coalesced dst load), ballots
// for destinations lacking a history entry (~1/20000 of edges), then the
// whole wave computes each qualifying edge's 64-channel message
// (lane = output channel) and atomically accumulates into out[dst].
__global__ void edge_fused(const float* __restrict__ x,
                           const float* __restrict__ W,
                           const int* __restrict__ src,
                           const int* __restrict__ dst,
                           const int* __restrict__ et,
                           const int* __restrict__ hmap,
                           float* __restrict__ out) {
    int gtid = blockIdx.x * blockDim.x + threadIdx.x;
    int wave = gtid >> 6;
    int lane = threadIdx.x & 63;
    int e0 = wave << 6;
    if (e0 >= NE) return;
    int e = e0 + lane;            // NE is a multiple of 64, no tail
    int d = dst[e];
    bool need = (hmap[d] < 0);
    unsigned long long mask = __ballot(need);
    while (mask) {
        int l = __ffsll((long long)mask) - 1;
        mask &= mask - 1;
        int ee = e0 + l;
        int dd = __shfl(d, l);
        int s  = src[ee];         // same addr all lanes -> broadcast
        int r  = et[ee];
        const float* xr = x + s * CH;
        const float* wr = W + r * CH * CH + lane;
        float acc = 0.0f;
#pragma unroll 8
        for (int i = 0; i < CH; ++i)
            acc += xr[i] * wr[i * CH];
        atomicAdd(out + dd * CH + lane, acc);
    }
}

extern "C" void kernel_launch(void* const* d_in, const int* in_sizes, int n_in,
                              void* d_out, int out_size, void* d_ws, size_t ws_size,
                              hipStream_t stream) {
    const float* x      = (const float*)d_in[0];
    const float* W      = (const float*)d_in[1];
    const float* loop_w = (const float*)d_in[2];
    const float* bias   = (const float*)d_in[3];
    const float* hist   = (const float*)d_in[4];
    const int*   src    = (const int*)d_in[5];
    const int*   dst    = (const int*)d_in[6];
    const int*   et     = (const int*)d_in[7];
    const int*   hmap   = (const int*)d_in[8];
    float* out = (float*)d_out;

    splice_selfloop<<<(NN * 16 + 255) / 256, 256, 0, stream>>>(
        x, loop_w, bias, hist, hmap, out);

    edge_fused<<<(NE + 255) / 256, 256, 0, stream>>>(
        x, W, src, dst, et, hmap, out);
}